// Round 3
// baseline (137.233 us; speedup 1.0000x reference)
//
#include <hip/hip_runtime.h>
#include <stdint.h>

typedef __bf16 bf16x8 __attribute__((ext_vector_type(8)));
typedef float  f32x4  __attribute__((ext_vector_type(4)));

#define B_TOT 16384
#define MB    32          // batches per block
#define NT    18          // conv2 K-tiles (1152/64)

// ws layout (byte offsets) — prep outputs only
#define OFF_W1T   0u         // [550][128] bf16
#define OFF_W2B   141312u    // [128][1152] bf16 (w2b[oc][pos*128+ic])
#define OFF_FCB   436224u    // [256][128] bf16
#define OFF_WH    501760u    // [32][512] bf16
#define OFF_BH    534528u    // [32] f32

__device__ const float d_maxv[22] = {
  9.f,1.f,1.f,10.f,3.f,254.f,1.f,1.f,235.f,8.f,
  9.f,250.f,29.f,1.f,1.f,8.f,1.f,1.f,6.f,3.f,1.f,2.f };

static __device__ __forceinline__ short f2bf(float f){
  union { float f; uint32_t u; } c; c.f = f;
  uint32_t r = (c.u + 0x7FFFu + ((c.u >> 16) & 1u)) >> 16;  // RNE
  return (short)r;
}
static __device__ __forceinline__ float bf2f(short s){
  union { uint32_t u; float f; } c; c.u = ((uint32_t)(uint16_t)s) << 16;
  return c.f;
}
// XOR-swizzled short index for [row][k] tiles (stride in shorts, mult of 64)
static __device__ __forceinline__ int swz(int row, int k, int stride){
  return row * stride + ((((k >> 3) ^ (row & 7)) << 3) | (k & 7));
}
static __device__ __forceinline__ uint32_t pkbf(float a, float b){
  return (uint32_t)(uint16_t)f2bf(fmaxf(a, 0.f))
       | ((uint32_t)(uint16_t)f2bf(fmaxf(b, 0.f)) << 16);
}

// ---------------- prep: repack weights to bf16 GEMM layouts ----------------
__global__ __launch_bounds__(256) void k_prep(
    const float* __restrict__ c1w, const float* __restrict__ c2w,
    const float* __restrict__ fcw, const float* __restrict__ a0w,
    const float* __restrict__ a1w, const float* __restrict__ vw,
    const float* __restrict__ a0b, const float* __restrict__ a1b,
    const float* __restrict__ vb,
    short* __restrict__ w1t, short* __restrict__ w2b, short* __restrict__ fcb,
    short* __restrict__ wh, float* __restrict__ bh)
{
  int i = blockIdx.x * 256 + threadIdx.x;
  if (i < 70400) {                    // w1t[r*128+oc] = c1w[oc*550 + r]
    int r = i >> 7, oc = i & 127;
    w1t[i] = f2bf(c1w[oc * 550 + r]);
  }
  i -= 70400;
  if (i >= 0 && i < 147456) {         // w2b[oc*1152 + pos*128+ic]
    int oc = i / 1152, k = i - oc * 1152;
    int pos = k >> 7, ic = k & 127;
    w2b[i] = f2bf(c2w[oc * 1152 + ic * 9 + pos]);
  }
  i -= 147456;
  if (i >= 0 && i < 32768) fcb[i] = f2bf(fcw[i]);
  i -= 32768;
  if (i >= 0 && i < 16384) {          // wh[j*512+k], j in [0,32)
    int j = i >> 9, k = i & 511;
    float v = 0.f;
    if (j < 9) v = a0w[j * 512 + k];
    else if (j < 19) v = a1w[(j - 9) * 512 + k];
    else if (j == 19) v = vw[k];
    wh[i] = f2bf(v);
  }
  i -= 16384;
  if (i >= 0 && i < 32) {
    float v = 0.f;
    if (i < 9) v = a0b[i]; else if (i < 19) v = a1b[i - 9]; else if (i == 19) v = vb[0];
    bh[i] = v;
  }
}

// ------------- fully fused: parse -> dedup -> conv1 -> conv2 -> fc -> heads -------------
__global__ __launch_bounds__(512, 1) void k_fused(
    const int* __restrict__ obs,
    const float* __restrict__ selfw, const float* __restrict__ selfb,
    const float* __restrict__ c1b, const short* __restrict__ w1t,
    const short* __restrict__ w2b, const short* __restrict__ fcb,
    const short* __restrict__ wh,  const float* __restrict__ c2b,
    const float* __restrict__ fcbias, const float* __restrict__ bh,
    float* __restrict__ out)
{
  __shared__ __align__(16) short h1s[MB * 1152];       // 73728 B; aliased by hacc4 in heads
  union SmemU {
    short bt[2][8192];                                 // conv2 B-tile dbuf, 32768 B
    struct {
      uint32_t nzl[MB * 48];                           // (m<<20)|(cell<<8)|v
      uint32_t nzf[MB * 48];                           // (cell<<8)|v, padded to x4
      float    selfv[MB * 22];
    } L;
  };
  __shared__ __align__(16) SmemU u;
  __shared__ __align__(16) short h2s[MB * 128];        // 8192 B
  __shared__ __align__(16) short cfs[MB * 256];        // 16384 B
  __shared__ __align__(16) short sfl[MB * 256];        // 16384 B (self features)
  __shared__ uint32_t cnt[MB], cnt2[MB];
  __shared__ float invS[22];

  const int tid  = threadIdx.x;
  const int wid  = tid >> 6;
  const int lane = tid & 63;
  const int l15  = lane & 15;
  const int kg   = lane >> 4;
  const int b0   = blockIdx.x * MB;
  const f32x4 z4 = {0.f, 0.f, 0.f, 0.f};

  if (tid < MB) { cnt[tid] = 0u; cnt2[tid] = 0u; }
  if (tid < 22) invS[tid] = 1.0f / (d_maxv[tid] + 1e-8f);
  for (int i = tid; i < MB * 22; i += 512) u.L.selfv[i] = 0.f;
  __syncthreads();

  // ---- P0: parse tokens (coalesced 12B/thread bursts) ----
  for (int i = tid; i < MB * 200; i += 512) {
    int g = i / 200, m = i - g * 200;
    const int* p = obs + ((size_t)(b0 + g) * 200 + m) * 3;
    int c = p[0], a = p[1], v = p[2];
    c = (c == 255) ? 0 : c;  a = (a == 255) ? 0 : a;  v = (v == 255) ? 0 : v;
    int x = (c >> 4) & 15, y = c & 15;
    if (x < 11 && y < 11 && a < 22) {
      uint32_t idx = atomicAdd(&cnt[g], 1u);
      if (idx < 48u)
        u.L.nzl[g * 48 + idx] =
          ((uint32_t)m << 20) | ((uint32_t)(a * 121 + x * 11 + y) << 8) | (uint32_t)v;
    }
  }
  __syncthreads();

  // ---- P1: dedup (last-write-wins = max m per cell), center-cell extract ----
  for (int r = 0; r < 4; ++r) {
    int g = r * 8 + wid;
    uint32_t n = cnt[g]; if (n > 48u) n = 48u;
    for (uint32_t i = lane; i < n; i += 64) {
      uint32_t e = u.L.nzl[g * 48 + i];
      uint32_t cell = (e >> 8) & 0xFFFu;
      bool win = true;
      for (uint32_t j = 0; j < n; ++j) {
        uint32_t ej = u.L.nzl[g * 48 + j];
        if (((ej >> 8) & 0xFFFu) == cell && ej > e) { win = false; break; }
      }
      if (win && (e & 255u)) {
        uint32_t id2 = atomicAdd(&cnt2[g], 1u);
        u.L.nzf[g * 48 + id2] = e & 0xFFFFFu;
        uint32_t l = cell / 121u;
        if (cell - l * 121u == 60u)                     // x=5,y=5
          u.L.selfv[g * 22 + l] = (float)(e & 255u) * invS[l];
      }
    }
  }
  __syncthreads();
  if (tid < MB) {                                       // pad nzf count to x4
    uint32_t m = cnt2[tid], pad = (4u - (m & 3u)) & 3u;
    for (uint32_t p2 = 0; p2 < pad; ++p2) u.L.nzf[tid * 48 + m + p2] = 0u;
    cnt2[tid] = m + pad;
  }
  __syncthreads();

  // ---- P2: self encoder -> sfl (swizzled bf16) ----
  {
    int row = tid >> 4, o0 = (tid & 15) * 16;
    const float* sv = &u.L.selfv[row * 22];
    #pragma unroll
    for (int j = 0; j < 16; j += 2) {
      float a0 = selfb[o0 + j], a1 = selfb[o0 + j + 1];
      #pragma unroll
      for (int l = 0; l < 22; ++l) {
        float s = sv[l];
        a0 += s * selfw[(o0 + j) * 22 + l];
        a1 += s * selfw[(o0 + j + 1) * 22 + l];
      }
      *(uint32_t*)&sfl[swz(row, o0 + j, 256)] = pkbf(a0, a1);
    }
  }

  // ---- P3: sparse conv1 -> h1s (wave per batch, 4 rounds, 4-deep nz unroll) ----
  for (int r = 0; r < 4; ++r) {
    int g = r * 8 + wid;
    int oc0 = lane * 2;
    float acc[9][2];
    float bz0 = c1b[oc0], bz1 = c1b[oc0 + 1];
    #pragma unroll
    for (int p = 0; p < 9; ++p) { acc[p][0] = bz0; acc[p][1] = bz1; }
    int n2 = (int)cnt2[g];
    for (int ii = 0; ii < n2; ii += 4) {
      #pragma unroll
      for (int uu = 0; uu < 4; ++uu) {
        uint32_t e = u.L.nzf[g * 48 + ii + uu];
        int v8 = (int)(e & 255u);
        int cell = (int)(e >> 8);
        int l = cell / 121, rem = cell - l * 121;
        int x = rem / 11,  y = rem - x * 11;
        float v = (float)v8 * invS[l];
        #pragma unroll
        for (int ox = 0; ox < 3; ++ox) {
          int kx = x - 3 * ox; if (kx < 0 || kx > 4) continue;
          #pragma unroll
          for (int oy = 0; oy < 3; ++oy) {
            int ky = y - 3 * oy; if (ky < 0 || ky > 4) continue;
            uint32_t wp = *(const uint32_t*)(const void*)
                          &w1t[(l * 25 + kx * 5 + ky) * 128 + oc0];
            acc[ox * 3 + oy][0] += v * bf2f((short)(wp & 0xFFFFu));
            acc[ox * 3 + oy][1] += v * bf2f((short)(wp >> 16));
          }
        }
      }
    }
    #pragma unroll
    for (int p = 0; p < 9; ++p)
      *(uint32_t*)&h1s[swz(g, p * 128 + oc0, 1152)] = pkbf(acc[p][0], acc[p][1]);
  }
  __syncthreads();

  // ---- P4: conv2 GEMM (M=32,N=128,K=1152), 2-phase reg-staged B pipeline ----
  const int wr = wid & 1;              // row half (16)
  const int wc = wid >> 1;             // col quarter (32)
  f32x4 c2acc[2] = {z4, z4};
  const int cA = tid, cB = 512 + tid;  // 16B chunks of the 16KB tile
  const int ocA = cA >> 3, ocB = cB >> 3;
  const short* gA = w2b + ocA * 1152 + (cA & 7) * 8;
  const short* gB = w2b + ocB * 1152 + (cB & 7) * 8;
  const int dA = ocA * 64 + (((cA & 7) ^ (ocA & 7)) << 3);
  const int dB = ocB * 64 + (((cB & 7) ^ (ocB & 7)) << 3);
  int4 va = *(const int4*)(const void*)gA;
  int4 vb = *(const int4*)(const void*)gB;
  for (int t = 0; t < NT; ++t) {
    const int buf = t & 1;
    *(int4*)(void*)&u.bt[buf][dA] = va;
    *(int4*)(void*)&u.bt[buf][dB] = vb;
    if (t < NT - 1) {
      va = *(const int4*)(const void*)(gA + (t + 1) * 64);
      vb = *(const int4*)(const void*)(gB + (t + 1) * 64);
    }
    asm volatile("s_waitcnt lgkmcnt(0)" ::: "memory");  // my ds_writes visible
    __builtin_amdgcn_s_barrier();                       // no vmcnt drain: prefetch flies
    __builtin_amdgcn_sched_barrier(0);
    #pragma unroll
    for (int ks = 0; ks < 2; ++ks) {
      int row = wr * 16 + l15;
      bf16x8 a = *(const bf16x8*)(const void*)&h1s[swz(row, t * 64 + ks * 32 + kg * 8, 1152)];
      #pragma unroll
      for (int nf = 0; nf < 2; ++nf) {
        int oc = wc * 32 + nf * 16 + l15;
        bf16x8 b = *(const bf16x8*)(const void*)&u.bt[buf][swz(oc, ks * 32 + kg * 8, 64)];
        c2acc[nf] = __builtin_amdgcn_mfma_f32_16x16x32_bf16(a, b, c2acc[nf], 0, 0, 0);
      }
    }
  }
  #pragma unroll
  for (int nf = 0; nf < 2; ++nf) {
    int col = wc * 32 + nf * 16 + l15;
    float bias = c2b[col];
    #pragma unroll
    for (int rr = 0; rr < 4; ++rr) {
      int row = wr * 16 + kg * 4 + rr;                  // C/D: col=lane&15, row=(lane>>4)*4+r
      h2s[swz(row, col, 128)] = f2bf(fmaxf(c2acc[nf][rr] + bias, 0.f));
    }
  }
  __syncthreads();

  // ---- P5: fc GEMM (M=32,N=256,K=128); B direct from L2 ----
  f32x4 fca[2][2] = {{z4, z4}, {z4, z4}};               // [rowgrp][nf]
  #pragma unroll
  for (int kk4 = 0; kk4 < 4; ++kk4) {
    int k = kk4 * 32 + kg * 8;
    bf16x8 a0 = *(const bf16x8*)(const void*)&h2s[swz(l15, k, 128)];
    bf16x8 a1 = *(const bf16x8*)(const void*)&h2s[swz(16 + l15, k, 128)];
    #pragma unroll
    for (int nf = 0; nf < 2; ++nf) {
      int col = wid * 32 + nf * 16 + l15;
      bf16x8 b = *(const bf16x8*)(const void*)(fcb + col * 128 + k);
      fca[0][nf] = __builtin_amdgcn_mfma_f32_16x16x32_bf16(a0, b, fca[0][nf], 0, 0, 0);
      fca[1][nf] = __builtin_amdgcn_mfma_f32_16x16x32_bf16(a1, b, fca[1][nf], 0, 0, 0);
    }
  }
  #pragma unroll
  for (int rg = 0; rg < 2; ++rg)
    #pragma unroll
    for (int nf = 0; nf < 2; ++nf) {
      int col = wid * 32 + nf * 16 + l15;
      float bias = fcbias[col];
      #pragma unroll
      for (int rr = 0; rr < 4; ++rr) {
        int row = rg * 16 + kg * 4 + rr;
        cfs[swz(row, col, 256)] = f2bf(fmaxf(fca[rg][nf][rr] + bias, 0.f));
      }
    }
  __syncthreads();

  // ---- P6: heads (M=32,N=32,K=512), K-split over 4 wave-groups, LDS partials ----
  float* hacc4 = (float*)h1s;                           // [4][32*32] f32 = 16KB, h1s dead
  {
    const int kq = wid >> 1;
    f32x4 ha[2] = {z4, z4};
    #pragma unroll
    for (int kk4 = 0; kk4 < 4; ++kk4) {
      int row = wr * 16 + l15;
      int kglob = kq * 128 + kk4 * 32 + kg * 8;
      bf16x8 a;
      if (kq < 2) a = *(const bf16x8*)(const void*)&sfl[swz(row, kglob, 256)];
      else        a = *(const bf16x8*)(const void*)&cfs[swz(row, kglob - 256, 256)];
      #pragma unroll
      for (int nf = 0; nf < 2; ++nf) {
        int ncol = nf * 16 + l15;
        bf16x8 b = *(const bf16x8*)(const void*)(wh + ncol * 512 + kglob);
        ha[nf] = __builtin_amdgcn_mfma_f32_16x16x32_bf16(a, b, ha[nf], 0, 0, 0);
      }
    }
    #pragma unroll
    for (int nf = 0; nf < 2; ++nf)
      #pragma unroll
      for (int rr = 0; rr < 4; ++rr) {
        int row = wr * 16 + kg * 4 + rr;
        hacc4[kq * 1024 + row * 32 + nf * 16 + l15] = ha[nf][rr];
      }
  }
  __syncthreads();

  // ---- P7: reduce partials + bias + scatter to out ----
  #pragma unroll
  for (int q = 0; q < 2; ++q) {
    int i = q * 512 + tid;
    int row = i >> 5, colh = i & 31;
    float v = hacc4[i] + hacc4[1024 + i] + hacc4[2048 + i] + hacc4[3072 + i] + bh[colh];
    int gr = b0 + row;
    if (colh < 9)        out[gr * 9 + colh] = v;                    // a0 [B][9]
    else if (colh < 19)  out[147456 + gr * 10 + (colh - 9)] = v;    // a1 [B][10]
    else if (colh == 19) out[311296 + gr] = v;                      // v  [B][1]
  }
}

extern "C" void kernel_launch(void* const* d_in, const int* in_sizes, int n_in,
                              void* d_out, int out_size, void* d_ws, size_t ws_size,
                              hipStream_t stream)
{
  const int*   obs = (const int*)  d_in[0];
  const float* c1w = (const float*)d_in[1];
  const float* c1b = (const float*)d_in[2];
  const float* c2w = (const float*)d_in[3];
  const float* c2b = (const float*)d_in[4];
  const float* fcw = (const float*)d_in[5];
  const float* fcbv= (const float*)d_in[6];
  const float* sw  = (const float*)d_in[7];
  const float* sb  = (const float*)d_in[8];
  const float* a0w = (const float*)d_in[9];
  const float* a0b = (const float*)d_in[10];
  const float* a1w = (const float*)d_in[11];
  const float* a1b = (const float*)d_in[12];
  const float* vw  = (const float*)d_in[13];
  const float* vb  = (const float*)d_in[14];

  char* ws = (char*)d_ws;
  short* w1t   = (short*)(ws + OFF_W1T);
  short* w2b   = (short*)(ws + OFF_W2B);
  short* fcb   = (short*)(ws + OFF_FCB);
  short* wh    = (short*)(ws + OFF_WH);
  float* bh    = (float*)(ws + OFF_BH);
  float* out   = (float*)d_out;

  k_prep<<<dim3(1044), dim3(256), 0, stream>>>(c1w, c2w, fcw, a0w, a1w, vw,
                                               a0b, a1b, vb, w1t, w2b, fcb, wh, bh);
  k_fused<<<dim3(B_TOT / MB), dim3(512), 0, stream>>>(obs, sw, sb, c1b, w1t, w2b, fcb,
                                                      wh, c2b, fcbv, bh, out);
}

// Round 4
// 109.292 us; speedup vs baseline: 1.2557x; 1.2557x over previous
//
#include <hip/hip_runtime.h>
#include <stdint.h>

typedef __bf16 bf16x8 __attribute__((ext_vector_type(8)));
typedef float  f32x4  __attribute__((ext_vector_type(4)));

#define B_TOT 16384
#define GS    4

// ws layout (byte offsets)
#define OFF_W1T   0u         // [550][128] bf16
#define OFF_W2B   141312u    // [128][1152] bf16 (w2b[oc][pos*128+ic])
#define OFF_FCB   436224u    // [256][128] bf16
#define OFF_WH    501760u    // [32][512] bf16 (head weights, N padded to 32)
#define OFF_BH    534528u    // [32] f32 head bias
#define OFF_SWT   534656u    // [22][256] f32 transposed self_w
#define OFF_SELFF 557184u    // [16384][256] bf16
#define OFF_H1    8945792u   // [16384][1152] bf16  (total ~44.5 MiB)

__device__ const float d_maxv[22] = {
  9.f,1.f,1.f,10.f,3.f,254.f,1.f,1.f,235.f,8.f,
  9.f,250.f,29.f,1.f,1.f,8.f,1.f,1.f,6.f,3.f,1.f,2.f };

static __device__ __forceinline__ short f2bf(float f){
  union { float f; uint32_t u; } c; c.f = f;
  uint32_t r = (c.u + 0x7FFFu + ((c.u >> 16) & 1u)) >> 16;  // RNE
  return (short)r;
}
static __device__ __forceinline__ float bf2f(short s){
  union { uint32_t u; float f; } c; c.u = ((uint32_t)(uint16_t)s) << 16;
  return c.f;
}
// XOR-swizzled short index for [row][k] LDS tiles (stride: shorts, mult of 64)
static __device__ __forceinline__ int swz(int row, int k, int stride){
  return row * stride + ((((k >> 3) ^ (row & 7)) << 3) | (k & 7));
}

// ---------------- prep: repack weights to bf16 GEMM layouts ----------------
__global__ __launch_bounds__(256) void k_prep(
    const float* __restrict__ c1w, const float* __restrict__ c2w,
    const float* __restrict__ fcw, const float* __restrict__ a0w,
    const float* __restrict__ a1w, const float* __restrict__ vw,
    const float* __restrict__ a0b, const float* __restrict__ a1b,
    const float* __restrict__ vb,  const float* __restrict__ selfw,
    short* __restrict__ w1t, short* __restrict__ w2b, short* __restrict__ fcb,
    short* __restrict__ wh, float* __restrict__ bh, float* __restrict__ swT)
{
  int i = blockIdx.x * 256 + threadIdx.x;
  if (i < 70400) {                    // w1t[r*128+oc] = c1w[oc*550 + r]
    int r = i >> 7, oc = i & 127;
    w1t[i] = f2bf(c1w[oc * 550 + r]);
  }
  i -= 70400;
  if (i >= 0 && i < 147456) {         // w2b[oc*1152 + pos*128+ic]
    int oc = i / 1152, k = i - oc * 1152;
    int pos = k >> 7, ic = k & 127;
    w2b[i] = f2bf(c2w[oc * 1152 + ic * 9 + pos]);
  }
  i -= 147456;
  if (i >= 0 && i < 32768) fcb[i] = f2bf(fcw[i]);   // fc_w already [n][k]
  i -= 32768;
  if (i >= 0 && i < 16384) {          // wh[j*512+k], j in [0,32)
    int j = i >> 9, k = i & 511;
    float v = 0.f;
    if (j < 9) v = a0w[j * 512 + k];
    else if (j < 19) v = a1w[(j - 9) * 512 + k];
    else if (j == 19) v = vw[k];
    wh[i] = f2bf(v);
  }
  i -= 16384;
  if (i >= 0 && i < 32) {
    float v = 0.f;
    if (i < 9) v = a0b[i]; else if (i < 19) v = a1b[i - 9]; else if (i == 19) v = vb[0];
    bh[i] = v;
  }
  i -= 32;
  if (i >= 0 && i < 5632) {           // swT[l*256+o] = selfw[o*22+l]
    int l = i >> 8, o = i & 255;
    swT[i] = selfw[o * 22 + l];
  }
}

// ---- scatter (sparse) + self-encoder + sparse conv1: 1 wave/batch, GS=4 ----
__global__ __launch_bounds__(256) void k_scatter(
    const int* __restrict__ obs, const float* __restrict__ swT,
    const float* __restrict__ selfb, const float* __restrict__ c1b,
    const short* __restrict__ w1t,
    short* __restrict__ selfF, short* __restrict__ h1)
{
  __shared__ alignas(16) int tok[GS * 600];  // staged obs tokens
  __shared__ uint32_t nzl[GS * 200];         // (m<<20)|(cell<<8)|v  valid tokens
  __shared__ uint32_t nzf[GS * 200];         // (cell<<8)|v  dedup'd winners, v>0
  __shared__ uint32_t cnt[GS], cnt2[GS];
  __shared__ float    selfv[GS * 22];        // center-cell feature per layer
  __shared__ float    invS[22];

  const int tid  = threadIdx.x;
  const int wid  = tid >> 6;
  const int lane = tid & 63;
  const int b0   = blockIdx.x * GS;
  const int b    = b0 + wid;

  if (tid < GS) { cnt[tid] = 0u; cnt2[tid] = 0u; }
  if (tid < 22) invS[tid] = 1.0f / (d_maxv[tid] + 1e-8f);
  for (int i = tid; i < GS * 22; i += 256) selfv[i] = 0.f;

  // stage obs: GS*600 ints contiguous, coalesced int4 loads
  {
    const int4* src = (const int4*)(obs + (size_t)b0 * 600);
    int4* dst = (int4*)tok;
    for (int i = tid; i < GS * 150; i += 256) dst[i] = src[i];
  }
  __syncthreads();

  // parse: wave wid -> batch wid; append valid tokens
  for (int m = lane; m < 200; m += 64) {
    int c = tok[wid * 600 + m * 3];
    int a = tok[wid * 600 + m * 3 + 1];
    int v = tok[wid * 600 + m * 3 + 2];
    c = (c == 255) ? 0 : c;  a = (a == 255) ? 0 : a;  v = (v == 255) ? 0 : v;
    int x = (c >> 4) & 15, y = c & 15;
    if (x < 11 && y < 11 && a < 22) {
      uint32_t cell = (uint32_t)(a * 121 + x * 11 + y);
      uint32_t idx = atomicAdd(&cnt[wid], 1u);
      nzl[wid * 200 + idx] = ((uint32_t)m << 20) | (cell << 8) | (uint32_t)v;
    }
  }
  __syncthreads();

  // dedup (last-write-wins = max m per cell), compact v>0 survivors,
  // extract center cell
  {
    const uint32_t n = cnt[wid];
    for (uint32_t i = lane; i < n; i += 64) {
      uint32_t e = nzl[wid * 200 + i];
      uint32_t cell = (e >> 8) & 0xFFFu;
      bool winner = true;
      for (uint32_t j = 0; j < n; ++j) {
        uint32_t ej = nzl[wid * 200 + j];
        if (((ej >> 8) & 0xFFFu) == cell && ej > e) { winner = false; break; }
      }
      if (winner && (e & 255u) != 0u) {
        uint32_t id2 = atomicAdd(&cnt2[wid], 1u);
        nzf[wid * 200 + id2] = e & 0xFFFFFu;
        uint32_t l = cell / 121u;
        if (cell - l * 121u == 60u)                 // x=5,y=5
          selfv[wid * 22 + l] = (float)(e & 255u) * invS[l];
      }
    }
  }
  __syncthreads();

  // self encoder: lane owns outputs 4*lane..4*lane+3; swT coalesced float4
  {
    float4 bv = ((const float4*)selfb)[lane];
    float acc[4] = {bv.x, bv.y, bv.z, bv.w};
    const float4* swT4 = (const float4*)swT;
    #pragma unroll
    for (int l = 0; l < 22; ++l) {
      float sv = selfv[wid * 22 + l];               // LDS broadcast
      float4 wv = swT4[l * 64 + lane];              // 16B/lane coalesced
      acc[0] += sv * wv.x; acc[1] += sv * wv.y;
      acc[2] += sv * wv.z; acc[3] += sv * wv.w;
    }
    uint32_t p0 = (uint32_t)(uint16_t)f2bf(fmaxf(acc[0], 0.f))
                | ((uint32_t)(uint16_t)f2bf(fmaxf(acc[1], 0.f)) << 16);
    uint32_t p1 = (uint32_t)(uint16_t)f2bf(fmaxf(acc[2], 0.f))
                | ((uint32_t)(uint16_t)f2bf(fmaxf(acc[3], 0.f)) << 16);
    uint32_t* dst = (uint32_t*)(selfF + (size_t)b * 256 + lane * 4);
    dst[0] = p0; dst[1] = p1;
  }

  // sparse conv1: lane owns oc = 2*lane, 2*lane+1
  {
    const int oc0 = lane * 2;
    float acc[9][2];
    const float bz0 = c1b[oc0], bz1 = c1b[oc0 + 1];
    #pragma unroll
    for (int p = 0; p < 9; ++p) { acc[p][0] = bz0; acc[p][1] = bz1; }
    const int n2 = (int)cnt2[wid];
    for (int ii = 0; ii < n2; ++ii) {
      uint32_t e = nzf[wid * 200 + ii];             // broadcast
      int v8 = (int)(e & 255u);
      int cell = (int)(e >> 8);
      int l = cell / 121, rem = cell - l * 121;
      int x = rem / 11,  y = rem - x * 11;
      float v = (float)v8 * invS[l];
      #pragma unroll
      for (int ox = 0; ox < 3; ++ox) {
        int kx = x - 3 * ox; if (kx < 0 || kx > 4) continue;
        #pragma unroll
        for (int oy = 0; oy < 3; ++oy) {
          int ky = y - 3 * oy; if (ky < 0 || ky > 4) continue;
          uint32_t wp = *(const uint32_t*)(const void*)
                        &w1t[(l * 25 + kx * 5 + ky) * 128 + oc0];
          acc[ox * 3 + oy][0] += v * bf2f((short)(wp & 0xFFFFu));
          acc[ox * 3 + oy][1] += v * bf2f((short)(wp >> 16));
        }
      }
    }
    uint32_t* dst = (uint32_t*)h1 + (size_t)b * 576 + lane;
    #pragma unroll
    for (int p = 0; p < 9; ++p) {
      uint32_t pk = (uint32_t)(uint16_t)f2bf(fmaxf(acc[p][0], 0.f))
                  | ((uint32_t)(uint16_t)f2bf(fmaxf(acc[p][1], 0.f)) << 16);
      dst[p * 64] = pk;
    }
  }
}

// ------- conv2 -> fc -> heads GEMM chain: 32 batches, 8 waves, reg-prefetch -------
__global__ __launch_bounds__(512, 4) void k_mlp(
    const short* __restrict__ h1, const short* __restrict__ selfF,
    const short* __restrict__ w2b, const short* __restrict__ fcb,
    const short* __restrict__ wh,  const float* __restrict__ c2b,
    const float* __restrict__ fcbias, const float* __restrict__ bh,
    float* __restrict__ out)
{
  __shared__ short h2s[32 * 128];   // 8KB, XOR-swizzled
  __shared__ short cfs[32 * 256];   // 16KB, XOR-swizzled
  __shared__ float hacc4[4][32 * 32]; // 16KB head partials

  const int tid = threadIdx.x;
  const int w   = tid >> 6;
  const int l   = tid & 63;
  const int l15 = l & 15;
  const int kg  = l >> 4;
  const int wr  = w & 1;            // row half (16)
  const int wc  = w >> 1;           // 0..3
  const size_t b0 = (size_t)blockIdx.x * 32;
  const int rowA = wr * 16 + l15;
  const f32x4 z4 = {0.f, 0.f, 0.f, 0.f};

  // ---- conv2 GEMM: M=32 N=128 K=1152; wave = 16 rows x 32 cols ----
  f32x4 acc0 = z4, acc1 = z4;
  const short* ap = h1 + (b0 + (size_t)rowA) * 1152 + kg * 8;
  const short* bp = w2b + (size_t)(wc * 32 + l15) * 1152 + kg * 8;
  bf16x8 a_c  = *(const bf16x8*)(const void*)ap;
  bf16x8 b0_c = *(const bf16x8*)(const void*)bp;
  bf16x8 b1_c = *(const bf16x8*)(const void*)(bp + 16 * 1152);
  for (int kk = 0; kk < 36; ++kk) {
    bf16x8 a_n = a_c, b0_n = b0_c, b1_n = b1_c;
    if (kk < 35) {                               // depth-1 register prefetch
      a_n  = *(const bf16x8*)(const void*)(ap + (kk + 1) * 32);
      b0_n = *(const bf16x8*)(const void*)(bp + (kk + 1) * 32);
      b1_n = *(const bf16x8*)(const void*)(bp + 16 * 1152 + (kk + 1) * 32);
    }
    acc0 = __builtin_amdgcn_mfma_f32_16x16x32_bf16(a_c, b0_c, acc0, 0, 0, 0);
    acc1 = __builtin_amdgcn_mfma_f32_16x16x32_bf16(a_c, b1_c, acc1, 0, 0, 0);
    a_c = a_n; b0_c = b0_n; b1_c = b1_n;
  }
  {
    int c0 = wc * 32 + l15, c1v = c0 + 16;
    float bz0 = c2b[c0], bz1 = c2b[c1v];
    #pragma unroll
    for (int rr = 0; rr < 4; ++rr) {             // C/D: col=lane&15, row=(lane>>4)*4+r
      int row = wr * 16 + kg * 4 + rr;
      h2s[swz(row, c0, 128)]  = f2bf(fmaxf(acc0[rr] + bz0, 0.f));
      h2s[swz(row, c1v, 128)] = f2bf(fmaxf(acc1[rr] + bz1, 0.f));
    }
  }
  __syncthreads();

  // ---- fc GEMM: M=32 N=256 K=128; wave = 16 rows x 64 cols ----
  f32x4 fca[4] = {z4, z4, z4, z4};
  const short* fp = fcb + (size_t)(wc * 64 + l15) * 128 + kg * 8;
  #pragma unroll
  for (int kk = 0; kk < 4; ++kk) {
    bf16x8 a = *(const bf16x8*)(const void*)&h2s[swz(rowA, kk * 32 + kg * 8, 128)];
    #pragma unroll
    for (int nf = 0; nf < 4; ++nf) {
      bf16x8 b = *(const bf16x8*)(const void*)(fp + nf * 16 * 128 + kk * 32);
      fca[nf] = __builtin_amdgcn_mfma_f32_16x16x32_bf16(a, b, fca[nf], 0, 0, 0);
    }
  }
  #pragma unroll
  for (int nf = 0; nf < 4; ++nf) {
    int col = wc * 64 + nf * 16 + l15;
    float bias = fcbias[col];
    #pragma unroll
    for (int rr = 0; rr < 4; ++rr) {
      int row = wr * 16 + kg * 4 + rr;
      cfs[swz(row, col, 256)] = f2bf(fmaxf(fca[nf][rr] + bias, 0.f));
    }
  }
  __syncthreads();

  // ---- heads: M=32 N=32 K=512, K-quarter per wc; LDS partials ----
  {
    f32x4 ha0 = z4, ha1 = z4;
    const short* sp = selfF + (b0 + (size_t)rowA) * 256 + (wc & 1) * 128 + kg * 8;
    #pragma unroll
    for (int kk = 0; kk < 4; ++kk) {
      int kglob = wc * 128 + kk * 32 + kg * 8;
      bf16x8 a;
      if (wc < 2) a = *(const bf16x8*)(const void*)(sp + kk * 32);
      else        a = *(const bf16x8*)(const void*)&cfs[swz(rowA, kglob - 256, 256)];
      bf16x8 bv0 = *(const bf16x8*)(const void*)(wh + l15 * 512 + kglob);
      bf16x8 bv1 = *(const bf16x8*)(const void*)(wh + (16 + l15) * 512 + kglob);
      ha0 = __builtin_amdgcn_mfma_f32_16x16x32_bf16(a, bv0, ha0, 0, 0, 0);
      ha1 = __builtin_amdgcn_mfma_f32_16x16x32_bf16(a, bv1, ha1, 0, 0, 0);
    }
    #pragma unroll
    for (int rr = 0; rr < 4; ++rr) {
      int row = wr * 16 + kg * 4 + rr;
      hacc4[wc][row * 32 + l15]      = ha0[rr];
      hacc4[wc][row * 32 + 16 + l15] = ha1[rr];
    }
  }
  __syncthreads();

  // ---- reduce partials + bias + scatter ----
  #pragma unroll
  for (int q = 0; q < 2; ++q) {
    int i = q * 512 + tid;
    int row = i >> 5, colh = i & 31;
    float v = hacc4[0][i] + hacc4[1][i] + hacc4[2][i] + hacc4[3][i] + bh[colh];
    int gr = (int)b0 + row;
    if (colh < 9)        out[gr * 9 + colh] = v;                    // a0 [B][9]
    else if (colh < 19)  out[147456 + gr * 10 + (colh - 9)] = v;    // a1 [B][10]
    else if (colh == 19) out[311296 + gr] = v;                      // v  [B][1]
  }
}

extern "C" void kernel_launch(void* const* d_in, const int* in_sizes, int n_in,
                              void* d_out, int out_size, void* d_ws, size_t ws_size,
                              hipStream_t stream)
{
  const int*   obs = (const int*)  d_in[0];
  const float* c1w = (const float*)d_in[1];
  const float* c1b = (const float*)d_in[2];
  const float* c2w = (const float*)d_in[3];
  const float* c2b = (const float*)d_in[4];
  const float* fcw = (const float*)d_in[5];
  const float* fcbv= (const float*)d_in[6];
  const float* sw  = (const float*)d_in[7];
  const float* sb  = (const float*)d_in[8];
  const float* a0w = (const float*)d_in[9];
  const float* a0b = (const float*)d_in[10];
  const float* a1w = (const float*)d_in[11];
  const float* a1b = (const float*)d_in[12];
  const float* vw  = (const float*)d_in[13];
  const float* vb  = (const float*)d_in[14];

  char* ws = (char*)d_ws;
  short* w1t   = (short*)(ws + OFF_W1T);
  short* w2b   = (short*)(ws + OFF_W2B);
  short* fcb   = (short*)(ws + OFF_FCB);
  short* wh    = (short*)(ws + OFF_WH);
  float* bh    = (float*)(ws + OFF_BH);
  float* swT   = (float*)(ws + OFF_SWT);
  short* selfF = (short*)(ws + OFF_SELFF);
  short* h1    = (short*)(ws + OFF_H1);
  float* out   = (float*)d_out;

  k_prep<<<dim3(1066), dim3(256), 0, stream>>>(c1w, c2w, fcw, a0w, a1w, vw,
                                               a0b, a1b, vb, sw,
                                               w1t, w2b, fcb, wh, bh, swT);
  k_scatter<<<dim3(B_TOT / GS), dim3(256), 0, stream>>>(obs, swT, sb, c1b, w1t, selfF, h1);
  k_mlp<<<dim3(B_TOT / 32), dim3(512), 0, stream>>>(h1, selfF, w2b, fcb, wh, c2b, fcbv, bh, out);
}

// Round 5
// 69.293 us; speedup vs baseline: 1.9805x; 1.5772x over previous
//
#include <hip/hip_runtime.h>
#include <stdint.h>

typedef __bf16 bf16x8 __attribute__((ext_vector_type(8)));
typedef float  f32x4  __attribute__((ext_vector_type(4)));

#define B_TOT 16384
#define GS    4
#define MB    64

// ws layout (byte offsets)
#define OFF_W1T   0u          // [550][128] bf16
#define OFF_W2B   141312u     // [128][1152] bf16 (w2b[oc][pos*128+ic])
#define OFF_FCB   436224u     // [256][128] bf16
#define OFF_WH    501760u     // [32][512] bf16 (head weights, N padded to 32)
#define OFF_BH    534528u     // [32] f32 head bias
#define OFF_SWB   534656u     // [256][32] bf16 self_w padded K 22->32
#define OFF_SELFV 551040u     // [16384][32] bf16 center-cell features (K-padded)
#define OFF_H1    1599616u    // [16384][1152] bf16  (total ~39.3 MiB)

__device__ const float d_maxv[22] = {
  9.f,1.f,1.f,10.f,3.f,254.f,1.f,1.f,235.f,8.f,
  9.f,250.f,29.f,1.f,1.f,8.f,1.f,1.f,6.f,3.f,1.f,2.f };

static __device__ __forceinline__ short f2bf(float f){
  union { float f; uint32_t u; } c; c.f = f;
  uint32_t r = (c.u + 0x7FFFu + ((c.u >> 16) & 1u)) >> 16;  // RNE
  return (short)r;
}
static __device__ __forceinline__ float bf2f(short s){
  union { uint32_t u; float f; } c; c.u = ((uint32_t)(uint16_t)s) << 16;
  return c.f;
}
// XOR-swizzled short index for [row][k] LDS tiles (stride: shorts, mult of 64)
static __device__ __forceinline__ int swz(int row, int k, int stride){
  return row * stride + ((((k >> 3) ^ (row & 7)) << 3) | (k & 7));
}
// async global->LDS, 16B per lane; lds dest = uniform base + lane*16
static __device__ __forceinline__ void gld16(const void* g, void* l){
  __builtin_amdgcn_global_load_lds(
      (const __attribute__((address_space(1))) void*)g,
      (__attribute__((address_space(3))) void*)l, 16, 0, 0);
}

// ---------------- prep: repack weights to bf16 GEMM layouts ----------------
__global__ __launch_bounds__(256) void k_prep(
    const float* __restrict__ c1w, const float* __restrict__ c2w,
    const float* __restrict__ fcw, const float* __restrict__ a0w,
    const float* __restrict__ a1w, const float* __restrict__ vw,
    const float* __restrict__ a0b, const float* __restrict__ a1b,
    const float* __restrict__ vb,  const float* __restrict__ selfw,
    short* __restrict__ w1t, short* __restrict__ w2b, short* __restrict__ fcb,
    short* __restrict__ wh, float* __restrict__ bh, short* __restrict__ swB)
{
  int i = blockIdx.x * 256 + threadIdx.x;
  if (i < 70400) {                    // w1t[r*128+oc] = c1w[oc*550 + r]
    int r = i >> 7, oc = i & 127;
    w1t[i] = f2bf(c1w[oc * 550 + r]);
  }
  i -= 70400;
  if (i >= 0 && i < 147456) {         // w2b[oc*1152 + pos*128+ic]
    int oc = i / 1152, k = i - oc * 1152;
    int pos = k >> 7, ic = k & 127;
    w2b[i] = f2bf(c2w[oc * 1152 + ic * 9 + pos]);
  }
  i -= 147456;
  if (i >= 0 && i < 32768) fcb[i] = f2bf(fcw[i]);   // fc_w already [n][k]
  i -= 32768;
  if (i >= 0 && i < 16384) {          // wh[j*512+k], j in [0,32)
    int j = i >> 9, k = i & 511;
    float v = 0.f;
    if (j < 9) v = a0w[j * 512 + k];
    else if (j < 19) v = a1w[(j - 9) * 512 + k];
    else if (j == 19) v = vw[k];
    wh[i] = f2bf(v);
  }
  i -= 16384;
  if (i >= 0 && i < 32) {
    float v = 0.f;
    if (i < 9) v = a0b[i]; else if (i < 19) v = a1b[i - 9]; else if (i == 19) v = vb[0];
    bh[i] = v;
  }
  i -= 32;
  if (i >= 0 && i < 8192) {           // swB[o*32+l] = selfw[o*22+l], K-pad 0
    int o = i >> 5, l = i & 31;
    swB[i] = (l < 22) ? f2bf(selfw[o * 22 + l]) : (short)0;
  }
}

// ---- scatter (sparse) + sparse conv1 + compact selfv: 1 wave/batch, GS=4 ----
__global__ __launch_bounds__(256) void k_scatter(
    const int* __restrict__ obs, const float* __restrict__ c1b,
    const short* __restrict__ w1t,
    short* __restrict__ selfvB, short* __restrict__ h1)
{
  __shared__ alignas(16) int tok[GS * 600];  // staged obs; later reused as h1 bounce
  __shared__ uint32_t nzl[GS * 200];         // (m<<20)|(cell<<8)|v  valid tokens
  __shared__ uint32_t nzf[GS * 200];         // (cell<<8)|v  dedup'd winners, v>0
  __shared__ uint32_t cnt[GS], cnt2[GS];
  __shared__ float    selfv[GS * 22];        // center-cell feature per layer
  __shared__ float    invS[22];

  const int tid  = threadIdx.x;
  const int wid  = tid >> 6;
  const int lane = tid & 63;
  const int b0   = blockIdx.x * GS;
  const int b    = b0 + wid;

  if (tid < GS) { cnt[tid] = 0u; cnt2[tid] = 0u; }
  if (tid < 22) invS[tid] = 1.0f / (d_maxv[tid] + 1e-8f);
  for (int i = tid; i < GS * 22; i += 256) selfv[i] = 0.f;

  // stage obs: GS*600 ints contiguous, coalesced int4 loads
  {
    const int4* src = (const int4*)(obs + (size_t)b0 * 600);
    int4* dst = (int4*)tok;
    for (int i = tid; i < GS * 150; i += 256) dst[i] = src[i];
  }
  __syncthreads();

  // parse: wave wid -> batch wid; append valid tokens
  for (int m = lane; m < 200; m += 64) {
    int c = tok[wid * 600 + m * 3];
    int a = tok[wid * 600 + m * 3 + 1];
    int v = tok[wid * 600 + m * 3 + 2];
    c = (c == 255) ? 0 : c;  a = (a == 255) ? 0 : a;  v = (v == 255) ? 0 : v;
    int x = (c >> 4) & 15, y = c & 15;
    if (x < 11 && y < 11 && a < 22) {
      uint32_t cell = (uint32_t)(a * 121 + x * 11 + y);
      uint32_t idx = atomicAdd(&cnt[wid], 1u);
      nzl[wid * 200 + idx] = ((uint32_t)m << 20) | (cell << 8) | (uint32_t)v;
    }
  }
  __syncthreads();

  // dedup (last-write-wins = max m per cell), compact v>0 survivors,
  // extract center cell
  {
    const uint32_t n = cnt[wid];
    for (uint32_t i = lane; i < n; i += 64) {
      uint32_t e = nzl[wid * 200 + i];
      uint32_t cell = (e >> 8) & 0xFFFu;
      bool winner = true;
      for (uint32_t j = 0; j < n; ++j) {
        uint32_t ej = nzl[wid * 200 + j];
        if (((ej >> 8) & 0xFFFu) == cell && ej > e) { winner = false; break; }
      }
      if (winner && (e & 255u) != 0u) {
        uint32_t id2 = atomicAdd(&cnt2[wid], 1u);
        nzf[wid * 200 + id2] = e & 0xFFFFFu;
        uint32_t l = cell / 121u;
        if (cell - l * 121u == 60u)                 // x=5,y=5
          selfv[wid * 22 + l] = (float)(e & 255u) * invS[l];
      }
    }
  }
  __syncthreads();

  // compact self features -> selfvB [b][32] bf16 (K-padded with zeros)
  if (lane < 16) {
    int l0 = lane * 2;
    float v0 = (l0     < 22) ? selfv[wid * 22 + l0]     : 0.f;
    float v1 = (l0 + 1 < 22) ? selfv[wid * 22 + l0 + 1] : 0.f;
    uint32_t pk = (uint32_t)(uint16_t)f2bf(v0) | ((uint32_t)(uint16_t)f2bf(v1) << 16);
    *(uint32_t*)(selfvB + (size_t)b * 32 + l0) = pk;
  }

  // sparse conv1: lane owns oc = 2*lane, 2*lane+1 -> LDS bounce -> wide stores
  short* h1row = (short*)tok;                   // tok dead; 4*2304B = 9216 <= 9600
  {
    const int oc0 = lane * 2;
    float acc[9][2];
    const float bz0 = c1b[oc0], bz1 = c1b[oc0 + 1];
    #pragma unroll
    for (int p = 0; p < 9; ++p) { acc[p][0] = bz0; acc[p][1] = bz1; }
    const int n2 = (int)cnt2[wid];
    for (int ii = 0; ii < n2; ++ii) {
      uint32_t e = nzf[wid * 200 + ii];         // broadcast
      int v8 = (int)(e & 255u);
      int cell = (int)(e >> 8);
      int l = cell / 121, rem = cell - l * 121;
      int x = rem / 11,  y = rem - x * 11;
      float v = (float)v8 * invS[l];
      #pragma unroll
      for (int ox = 0; ox < 3; ++ox) {
        int kx = x - 3 * ox; if (kx < 0 || kx > 4) continue;
        #pragma unroll
        for (int oy = 0; oy < 3; ++oy) {
          int ky = y - 3 * oy; if (ky < 0 || ky > 4) continue;
          uint32_t wp = *(const uint32_t*)(const void*)
                        &w1t[(l * 25 + kx * 5 + ky) * 128 + oc0];
          acc[ox * 3 + oy][0] += v * bf2f((short)(wp & 0xFFFFu));
          acc[ox * 3 + oy][1] += v * bf2f((short)(wp >> 16));
        }
      }
    }
    #pragma unroll
    for (int p = 0; p < 9; ++p) {
      uint32_t pk = (uint32_t)(uint16_t)f2bf(fmaxf(acc[p][0], 0.f))
                  | ((uint32_t)(uint16_t)f2bf(fmaxf(acc[p][1], 0.f)) << 16);
      *(uint32_t*)&h1row[wid * 1152 + p * 128 + oc0] = pk;
    }
  }
  __syncthreads();
  {
    const int4* src4 = (const int4*)h1row;
    int4* dst4 = (int4*)(h1 + (size_t)b0 * 1152);
    for (int i = tid; i < GS * 144; i += 256) dst4[i] = src4[i];
  }
}

// ----- conv2 -> fc -> self -> heads: 64 batches/block, LDS-staged dbuf GEMM -----
__global__ __launch_bounds__(512, 2) void k_mlp(
    const short* __restrict__ h1, const short* __restrict__ selfvB,
    const short* __restrict__ w2b, const short* __restrict__ fcb,
    const short* __restrict__ wh,  const short* __restrict__ swB,
    const float* __restrict__ c2b, const float* __restrict__ fcbias,
    const float* __restrict__ selfb, const float* __restrict__ bh,
    float* __restrict__ out)
{
  // short-index regions:
  //  staging dbuf: [0,24576) = 2 x { A [0,4096) + B [4096,12288) }
  //  h2s [0,8192) stride 128 | cfs [8192,24576) stride 256 | sfl [24576,40960) stride 256
  //  hacc (float*)smem: floats [0,4096) (aliases h2s region only)
  __shared__ __align__(16) short smem[40960];   // 80 KiB

  const int tid  = threadIdx.x;
  const int wid  = tid >> 6;
  const int lane = tid & 63;
  const int l15  = lane & 15;
  const int kg   = lane >> 4;
  const int wr   = wid & 3;          // 4 row-groups of 16
  const int wc   = wid >> 2;         // 2 col-groups
  const int rowA = wr * 16 + l15;
  const size_t b0 = (size_t)blockIdx.x * MB;
  const f32x4 z4 = {0.f, 0.f, 0.f, 0.f};

  // ---- conv2 GEMM: M=64 N=128 K=1152, BK=64, double-buffered LDS staging ----
  // 24 stage-insts/step (A:8, B:16), wave w issues insts 3w..3w+2.
  const short* gst[3];
  int lbase[3];
  {
    const int sub = lane >> 3, pch = lane & 7;
    #pragma unroll
    for (int j = 0; j < 3; ++j) {
      int ii = wid * 3 + j;
      if (ii < 8) {                       // A rows 8ii..8ii+7
        int row = ii * 8 + sub;
        int kc  = pch ^ (row & 7);        // inverse-swizzled source chunk
        gst[j] = h1 + (b0 + row) * 1152 + kc * 8;
        lbase[j] = ii * 512;
      } else {                            // B rows (oc) 8j..8j+7
        int jb = ii - 8;
        int oc = jb * 8 + sub;
        int kc = pch ^ (oc & 7);
        gst[j] = w2b + (size_t)oc * 1152 + kc * 8;
        lbase[j] = 4096 + jb * 512;
      }
    }
  }
  f32x4 acc[4] = {z4, z4, z4, z4};
  #pragma unroll
  for (int j = 0; j < 3; ++j) gld16(gst[j], &smem[lbase[j]]);   // stage t=0 -> buf0
  __syncthreads();

  for (int t = 0; t < 18; ++t) {
    const int cb = (t & 1) * 12288;
    if (t < 17) {
      const int nb = ((t + 1) & 1) * 12288;
      #pragma unroll
      for (int j = 0; j < 3; ++j) gld16(gst[j] + (t + 1) * 64, &smem[nb + lbase[j]]);
    }
    #pragma unroll
    for (int ks = 0; ks < 2; ++ks) {
      bf16x8 a = *(const bf16x8*)(const void*)
                 &smem[cb + rowA * 64 + ((((ks * 4 + kg) ^ (rowA & 7))) << 3)];
      #pragma unroll
      for (int nf = 0; nf < 4; ++nf) {
        int oc = wc * 64 + nf * 16 + l15;
        bf16x8 b = *(const bf16x8*)(const void*)
                   &smem[cb + 4096 + oc * 64 + ((((ks * 4 + kg) ^ (oc & 7))) << 3)];
        acc[nf] = __builtin_amdgcn_mfma_f32_16x16x32_bf16(a, b, acc[nf], 0, 0, 0);
      }
    }
    __syncthreads();    // drains my stage (vmcnt) + all waves' reads of cb
  }
  // epilogue: bias+relu -> h2s [0,8192)
  #pragma unroll
  for (int nf = 0; nf < 4; ++nf) {
    int col = wc * 64 + nf * 16 + l15;
    float bias = c2b[col];
    #pragma unroll
    for (int rr = 0; rr < 4; ++rr) {      // C/D: col=lane&15, row=(lane>>4)*4+rr
      int row = wr * 16 + kg * 4 + rr;
      smem[swz(row, col, 128)] = f2bf(fmaxf(acc[nf][rr] + bias, 0.f));
    }
  }
  __syncthreads();

  // ---- fc GEMM: M=64 N=256 K=128; A from h2s LDS, B from L2 ----
  {
    f32x4 fca[8] = {z4, z4, z4, z4, z4, z4, z4, z4};
    #pragma unroll
    for (int kk = 0; kk < 4; ++kk) {
      int k = kk * 32 + kg * 8;
      bf16x8 a = *(const bf16x8*)(const void*)&smem[swz(rowA, k, 128)];
      #pragma unroll
      for (int nf = 0; nf < 8; ++nf) {
        int col = wc * 128 + nf * 16 + l15;
        bf16x8 b = *(const bf16x8*)(const void*)(fcb + (size_t)col * 128 + k);
        fca[nf] = __builtin_amdgcn_mfma_f32_16x16x32_bf16(a, b, fca[nf], 0, 0, 0);
      }
    }
    #pragma unroll
    for (int nf = 0; nf < 8; ++nf) {
      int col = wc * 128 + nf * 16 + l15;
      float bias = fcbias[col];
      #pragma unroll
      for (int rr = 0; rr < 4; ++rr) {
        int row = wr * 16 + kg * 4 + rr;
        smem[8192 + swz(row, col, 256)] = f2bf(fmaxf(fca[nf][rr] + bias, 0.f));
      }
    }
  }

  // ---- self encoder as GEMM: M=64 N=256 K=32; A,B from L2 -> sfl LDS ----
  {
    f32x4 sa[8] = {z4, z4, z4, z4, z4, z4, z4, z4};
    bf16x8 a = *(const bf16x8*)(const void*)(selfvB + (b0 + rowA) * 32 + kg * 8);
    #pragma unroll
    for (int nf = 0; nf < 8; ++nf) {
      int col = wc * 128 + nf * 16 + l15;
      bf16x8 b = *(const bf16x8*)(const void*)(swB + (size_t)col * 32 + kg * 8);
      sa[nf] = __builtin_amdgcn_mfma_f32_16x16x32_bf16(a, b, sa[nf], 0, 0, 0);
    }
    #pragma unroll
    for (int nf = 0; nf < 8; ++nf) {
      int col = wc * 128 + nf * 16 + l15;
      float bias = selfb[col];
      #pragma unroll
      for (int rr = 0; rr < 4; ++rr) {
        int row = wr * 16 + kg * 4 + rr;
        smem[24576 + swz(row, col, 256)] = f2bf(fmaxf(sa[nf][rr] + bias, 0.f));
      }
    }
  }
  __syncthreads();

  // ---- heads: M=64 N=32 K=512 (0..255 self | 256..511 cnn), K-half per wc ----
  {
    float* hacc = (float*)smem;                 // [2][2048] f32, aliases h2s only
    f32x4 ha0 = z4, ha1 = z4;
    #pragma unroll
    for (int kk = 0; kk < 8; ++kk) {
      int kl = kk * 32 + kg * 8;
      bf16x8 a;
      if (wc == 0) a = *(const bf16x8*)(const void*)&smem[24576 + swz(rowA, kl, 256)];
      else         a = *(const bf16x8*)(const void*)&smem[8192  + swz(rowA, kl, 256)];
      int kglob = wc * 256 + kl;
      bf16x8 bv0 = *(const bf16x8*)(const void*)(wh + (size_t)l15 * 512 + kglob);
      bf16x8 bv1 = *(const bf16x8*)(const void*)(wh + (size_t)(16 + l15) * 512 + kglob);
      ha0 = __builtin_amdgcn_mfma_f32_16x16x32_bf16(a, bv0, ha0, 0, 0, 0);
      ha1 = __builtin_amdgcn_mfma_f32_16x16x32_bf16(a, bv1, ha1, 0, 0, 0);
    }
    #pragma unroll
    for (int rr = 0; rr < 4; ++rr) {
      int row = wr * 16 + kg * 4 + rr;
      hacc[wc * 2048 + row * 32 + l15]      = ha0[rr];
      hacc[wc * 2048 + row * 32 + 16 + l15] = ha1[rr];
    }
  }
  __syncthreads();

  // ---- reduce K-halves + bias + scatter ----
  {
    const float* hacc = (const float*)smem;
    #pragma unroll
    for (int q = 0; q < 4; ++q) {
      int i = q * 512 + tid;
      int row = i >> 5, colh = i & 31;
      float v = hacc[i] + hacc[2048 + i] + bh[colh];
      int gr = (int)b0 + row;
      if (colh < 9)        out[gr * 9 + colh] = v;                    // a0 [B][9]
      else if (colh < 19)  out[147456 + gr * 10 + (colh - 9)] = v;    // a1 [B][10]
      else if (colh == 19) out[311296 + gr] = v;                      // v  [B][1]
    }
  }
}

extern "C" void kernel_launch(void* const* d_in, const int* in_sizes, int n_in,
                              void* d_out, int out_size, void* d_ws, size_t ws_size,
                              hipStream_t stream)
{
  const int*   obs = (const int*)  d_in[0];
  const float* c1w = (const float*)d_in[1];
  const float* c1b = (const float*)d_in[2];
  const float* c2w = (const float*)d_in[3];
  const float* c2b = (const float*)d_in[4];
  const float* fcw = (const float*)d_in[5];
  const float* fcbv= (const float*)d_in[6];
  const float* sw  = (const float*)d_in[7];
  const float* sb  = (const float*)d_in[8];
  const float* a0w = (const float*)d_in[9];
  const float* a0b = (const float*)d_in[10];
  const float* a1w = (const float*)d_in[11];
  const float* a1b = (const float*)d_in[12];
  const float* vw  = (const float*)d_in[13];
  const float* vb  = (const float*)d_in[14];

  char* ws = (char*)d_ws;
  short* w1t   = (short*)(ws + OFF_W1T);
  short* w2b   = (short*)(ws + OFF_W2B);
  short* fcb   = (short*)(ws + OFF_FCB);
  short* wh    = (short*)(ws + OFF_WH);
  float* bh    = (float*)(ws + OFF_BH);
  short* swB   = (short*)(ws + OFF_SWB);
  short* selfvB= (short*)(ws + OFF_SELFV);
  short* h1    = (short*)(ws + OFF_H1);
  float* out   = (float*)d_out;

  k_prep<<<dim3(1076), dim3(256), 0, stream>>>(c1w, c2w, fcw, a0w, a1w, vw,
                                               a0b, a1b, vb, sw,
                                               w1t, w2b, fcb, wh, bh, swB);
  k_scatter<<<dim3(B_TOT / GS), dim3(256), 0, stream>>>(obs, c1b, w1t, selfvB, h1);
  k_mlp<<<dim3(B_TOT / MB), dim3(512), 0, stream>>>(h1, selfvB, w2b, fcb, wh, swB,
                                                    c2b, fcbv, sb, bh, out);
}